// Round 7
// baseline (91.077 us; speedup 1.0000x reference)
//
#include <hip/hip_runtime.h>

typedef float f32x4 __attribute__((ext_vector_type(4)));
typedef __bf16 bf16x8 __attribute__((ext_vector_type(8)));
typedef unsigned short u16x8 __attribute__((ext_vector_type(8)));

__device__ __forceinline__ unsigned short f2bf(float f) {
  union { float f; unsigned u; } v; v.f = f;
  unsigned r = v.u + 0x7FFFu + ((v.u >> 16) & 1u);
  return (unsigned short)(r >> 16);
}

__device__ __forceinline__ float min3f(float a, float b, float c) {
  return fminf(fminf(a, b), c);
}
__device__ __forceinline__ float max3f(float a, float b, float c) {
  return fmaxf(fmaxf(a, b), c);
}
__device__ __forceinline__ float med3f(float a, float b, float c) {
  return __builtin_amdgcn_fmed3f(a, b, c);
}

// async global->LDS, 16B per lane, LDS dest = wave-uniform base + lane*16
__device__ __forceinline__ void gload_lds16(const void* g, void* l) {
  __builtin_amdgcn_global_load_lds(
      (const __attribute__((address_space(1))) void*)g,
      (__attribute__((address_space(3))) void*)l, 16, 0, 0);
}

// conv_w fp32 [256][256] -> bf16 in MFMA-fragment-linear order:
// wbf[((ks*16 + ob)*64 + lane)*8 + j] = bf16(W[ob*16 + (lane&15)][ks*32 + (lane>>4)*8 + j])
__global__ void wconv_k(const float* __restrict__ w, unsigned short* __restrict__ wbf) {
  int idx  = blockIdx.x * 256 + threadIdx.x;   // 0..8191
  int lane = idx & 63;
  int ob   = (idx >> 6) & 15;
  int ks   = idx >> 10;                        // 0..7
  int o = (ob << 4) + (lane & 15);
  int c = (ks << 5) + ((lane >> 4) << 3);
  const float* src = w + (o << 8) + c;
  f32x4 v0 = *(const f32x4*)src;
  f32x4 v1 = *(const f32x4*)(src + 4);
  u16x8 ov;
  ov[0] = f2bf(v0[0]); ov[1] = f2bf(v0[1]); ov[2] = f2bf(v0[2]); ov[3] = f2bf(v0[3]);
  ov[4] = f2bf(v1[0]); ov[5] = f2bf(v1[1]); ov[6] = f2bf(v1[2]); ov[7] = f2bf(v1[3]);
  *(u16x8*)(wbf + (idx << 3)) = ov;
}

// One block = one (batch, row). 1 barrier per K-step: double-buffered Xs
// (gload_lds, 2-step-ahead) + double-buffered Bt; halo via lane shuffles.
__launch_bounds__(256, 2)
__global__ void fused_k(const float* __restrict__ x,
                        const unsigned short* __restrict__ wbf,
                        const float* __restrict__ bias,
                        float* __restrict__ out) {
  __shared__ float Xs[2][96][64];            // 48 KB, px-block pre-swizzled
  __shared__ unsigned short Bt[2][64][40];   // 10 KB med tiles [px][c-swizzled]

  const int t   = threadIdx.x;
  const int blk = blockIdx.x;
  const int swz = ((blk & 7) << 8) | (blk >> 3);   // XCD-bijective (2048 = 8*256)
  const int b   = swz >> 6;
  const int r   = swz & 63;
  const int lane = t & 63;
  const int w    = t >> 6;       // wave 0..3
  const int g    = lane >> 4;    // lane group 0..3
  const int l15  = lane & 15;

  // median task: channel ci = t>>3 (0..31), pixel strip s = t&7 (8 px)
  const int ci  = t >> 3;
  const int s   = t & 7;
  const int px0 = s << 3;
  const int cw  = ci ^ ((s & 3) << 3);   // Bt bank-deconflict swizzle
  const bool rT = (r >= 1), rB = (r <= 62);
  const bool hasL = (s > 0), hasR = (s < 7);

  const float* xb = x + ((size_t)b << 20);   // b * 256*64*64

  // bias for this thread's 4 o-blocks (o = w*64 + n*16 + l15)
  float bn[4];
  #pragma unroll
  for (int n = 0; n < 4; ++n) bn[n] = bias[(w << 6) + (n << 4) + l15];

  // --- staging source byte-offsets (wave w stages rows w*24 .. w*24+23) ---
  unsigned soff[6];
  #pragma unroll
  for (int p = 0; p < 6; ++p) {
    int row = w * 24 + (p << 2) + (lane >> 4);
    int cip = (row * 171) >> 9;            // row / 3 (exact for row < 96)
    int drp = row - cip * 3;
    int gr  = r + drp - 1;
    gr = gr < 0 ? 0 : (gr > 63 ? 63 : gr); // clamp; zeroed in VALU at median time
    int bG  = (lane & 15) ^ (cip & 7);     // pre-swizzled global px-block
    soff[p] = ((unsigned)cip << 14) + ((unsigned)gr << 8) + ((unsigned)bG << 4);
  }

  // loop-invariant swizzled LDS read block indices
  const int ri0 = ci * 3;
  const int sig = ci & 7;
  const int bAi = ((s << 1)) ^ sig;
  const int bBi = ((s << 1) | 1) ^ sig;

  auto stage = [&](int step, int buf) {
    const unsigned kso = (unsigned)step << 19;   // step * 32ch * 4096px * 4B
    #pragma unroll
    for (int p = 0; p < 6; ++p)
      gload_lds16((const char*)xb + (soff[p] + kso), &Xs[buf][w * 24 + (p << 2)][0]);
  };

  auto median_store = [&](int bufx, int bufb) {
    f32x4 va[3], vb[3];
    #pragma unroll
    for (int dr = 0; dr < 3; ++dr) {
      const float* rp = &Xs[bufx][ri0 + dr][0];
      va[dr] = *(const f32x4*)(rp + (bAi << 2));
      vb[dr] = *(const f32x4*)(rp + (bBi << 2));
    }
    float R[3][10];
    #pragma unroll
    for (int dr = 0; dr < 3; ++dr) {
      float le = __shfl_up(vb[dr][3], 1);    // left halo from lane-1 (same wave)
      float re = __shfl_down(va[dr][0], 1);  // right halo from lane+1
      R[dr][0] = hasL ? le : 0.f;
      R[dr][9] = hasR ? re : 0.f;
      #pragma unroll
      for (int j = 0; j < 4; ++j) { R[dr][1 + j] = va[dr][j]; R[dr][5 + j] = vb[dr][j]; }
    }
    if (!rT) {                     // uniform per block (r==0 only)
      #pragma unroll
      for (int j = 0; j < 10; ++j) R[0][j] = 0.f;
    }
    if (!rB) {                     // uniform per block (r==63 only)
      #pragma unroll
      for (int j = 0; j < 10; ++j) R[2][j] = 0.f;
    }
    float mn[10], md[10], mx[10];
    #pragma unroll
    for (int j = 0; j < 10; ++j) {
      mn[j] = min3f(R[0][j], R[1][j], R[2][j]);
      md[j] = med3f(R[0][j], R[1][j], R[2][j]);
      mx[j] = max3f(R[0][j], R[1][j], R[2][j]);
    }
    #pragma unroll
    for (int i = 0; i < 8; ++i) {
      float t0 = max3f(mn[i], mn[i+1], mn[i+2]);
      float t1 = med3f(md[i], md[i+1], md[i+2]);
      float t2 = min3f(mx[i], mx[i+1], mx[i+2]);
      Bt[bufb][px0 + i][cw] = f2bf(med3f(t0, t1, t2));
    }
  };

  f32x4 acc[4][4];
  #pragma unroll
  for (int m = 0; m < 4; ++m)
    #pragma unroll
    for (int n = 0; n < 4; ++n)
      acc[m][n] = (f32x4){0.f, 0.f, 0.f, 0.f};

  // --- prologue: two tiles in flight, median(0) published ---
  stage(0, 0);
  stage(1, 1);
  __syncthreads();               // drains both stages (forced vmcnt0)
  median_store(0, 0);
  __syncthreads();               // publish Bt[0]

  #pragma unroll
  for (int ks = 0; ks < 8; ++ks) {
    // issue stage ks+2 first: in flight across median+MFMA, drains at step barrier
    if (ks < 6) stage(ks + 2, ks & 1);

    // W fragments (L2-hot, coalesced), consumed by MFMA at step end
    bf16x8 wf[4];
    #pragma unroll
    for (int n = 0; n < 4; ++n) {
      const int fidx = (((ks << 4) + (w << 2) + n) << 6) + lane;
      wf[n] = __builtin_bit_cast(bf16x8, *(const u16x8*)(wbf + ((size_t)fidx << 3)));
    }

    // median for step ks+1 (overlaps this step's MFMA region across waves)
    if (ks < 7) median_store((ks + 1) & 1, (ks + 1) & 1);

    // P fragments (med tile, A-operand) from Bt[ks&1]
    bf16x8 pa[4];
    #pragma unroll
    for (int m = 0; m < 4; ++m) {
      const int px = (m << 4) + l15;
      const int gc = (g ^ ((px >> 3) & 3)) << 3;
      pa[m] = __builtin_bit_cast(bf16x8, *(const u16x8*)&Bt[ks & 1][px][gc]);
    }

    __builtin_amdgcn_s_setprio(1);
    #pragma unroll
    for (int m = 0; m < 4; ++m)
      #pragma unroll
      for (int n = 0; n < 4; ++n)
        acc[m][n] = __builtin_amdgcn_mfma_f32_16x16x32_bf16(pa[m], wf[n], acc[m][n], 0, 0, 0);
    __builtin_amdgcn_s_setprio(0);

    if (ks < 7) __syncthreads();   // single per-step barrier (drains stage ks+2)
  }

  // --- epilogue: out = x + acc + bias; q maps to px -> f32x4 I/O ---
  // C layout: row = g*4+q -> px = m*16+g*4+q ; col = l15 -> o = w*64+n*16+l15
  #pragma unroll
  for (int m = 0; m < 4; ++m) {
    #pragma unroll
    for (int n = 0; n < 4; ++n) {
      const int o = (w << 6) + (n << 4) + l15;
      const size_t idx = ((((size_t)b << 8) + (size_t)o) << 12) + ((size_t)r << 6)
                       + (size_t)((m << 4) + (g << 2));
      f32x4 xv = *(const f32x4*)(x + idx);
      f32x4 res;
      #pragma unroll
      for (int q = 0; q < 4; ++q) res[q] = xv[q] + acc[m][n][q] + bn[n];
      *(f32x4*)(out + idx) = res;
    }
  }
}

extern "C" void kernel_launch(void* const* d_in, const int* in_sizes, int n_in,
                              void* d_out, int out_size, void* d_ws, size_t ws_size,
                              hipStream_t stream) {
  const float* x  = (const float*)d_in[0];
  const float* cw = (const float*)d_in[1];
  const float* cb = (const float*)d_in[2];
  float* out = (float*)d_out;
  unsigned short* wbf = (unsigned short*)d_ws;   // 128 KB fragment-linear W

  hipLaunchKernelGGL(wconv_k, dim3(32), dim3(256), 0, stream, cw, wbf);
  hipLaunchKernelGGL(fused_k, dim3(2048), dim3(256), 0, stream, x, wbf, cb, out);
}

// Round 8
// 81.455 us; speedup vs baseline: 1.1181x; 1.1181x over previous
//
#include <hip/hip_runtime.h>

typedef float f32x4 __attribute__((ext_vector_type(4)));
typedef __bf16 bf16x8 __attribute__((ext_vector_type(8)));
typedef unsigned short u16x8 __attribute__((ext_vector_type(8)));

__device__ __forceinline__ unsigned short f2bf(float f) {
  union { float f; unsigned u; } v; v.f = f;
  unsigned r = v.u + 0x7FFFu + ((v.u >> 16) & 1u);
  return (unsigned short)(r >> 16);
}

__device__ __forceinline__ float min3f(float a, float b, float c) {
  return fminf(fminf(a, b), c);
}
__device__ __forceinline__ float max3f(float a, float b, float c) {
  return fmaxf(fmaxf(a, b), c);
}
__device__ __forceinline__ float med3f(float a, float b, float c) {
  return __builtin_amdgcn_fmed3f(a, b, c);
}

// async global->LDS, 16B per lane, LDS dest = wave-uniform base + lane*16
__device__ __forceinline__ void gload_lds16(const void* g, void* l) {
  __builtin_amdgcn_global_load_lds(
      (const __attribute__((address_space(1))) void*)g,
      (__attribute__((address_space(3))) void*)l, 16, 0, 0);
}

// conv_w fp32 [256][256] -> bf16 in MFMA-fragment-linear order:
// wbf[((ks*16 + ob)*64 + lane)*8 + j] = bf16(W[ob*16 + (lane&15)][ks*32 + (lane>>4)*8 + j])
__global__ void wconv_k(const float* __restrict__ w, unsigned short* __restrict__ wbf) {
  int idx  = blockIdx.x * 256 + threadIdx.x;   // 0..8191
  int lane = idx & 63;
  int ob   = (idx >> 6) & 15;
  int ks   = idx >> 10;                        // 0..7
  int o = (ob << 4) + (lane & 15);
  int c = (ks << 5) + ((lane >> 4) << 3);
  const float* src = w + (o << 8) + c;
  f32x4 v0 = *(const f32x4*)src;
  f32x4 v1 = *(const f32x4*)(src + 4);
  u16x8 ov;
  ov[0] = f2bf(v0[0]); ov[1] = f2bf(v0[1]); ov[2] = f2bf(v0[2]); ov[3] = f2bf(v0[3]);
  ov[4] = f2bf(v1[0]); ov[5] = f2bf(v1[1]); ov[6] = f2bf(v1[2]); ov[7] = f2bf(v1[3]);
  *(u16x8*)(wbf + (idx << 3)) = ov;
}

// One block = one (batch, row). Xs is WAVE-PRIVATE (wave w stages rows
// 24w..24w+23 = channels 8w..8w+8 and medians only those) -> no barrier for
// Xs, only per-wave counted vmcnt. Bt double-buffered -> 1 raw s_barrier per
// step (no vmcnt drain): stage(ks+1) stays in flight across barrier+pa+MFMA.
__launch_bounds__(256, 3)
__global__ void fused_k(const float* __restrict__ x,
                        const unsigned short* __restrict__ wbf,
                        const float* __restrict__ bias,
                        float* __restrict__ out) {
  __shared__ float Xs[96][64];               // 24 KB, px-block pre-swizzled
  __shared__ unsigned short Bt[2][64][40];   // 10 KB med tiles [px][c-swizzled]

  const int t   = threadIdx.x;
  const int blk = blockIdx.x;
  const int swz = ((blk & 7) << 8) | (blk >> 3);   // XCD-bijective (2048 = 8*256)
  const int b   = swz >> 6;
  const int r   = swz & 63;
  const int lane = t & 63;
  const int w    = t >> 6;       // wave 0..3
  const int g    = lane >> 4;    // lane group 0..3
  const int l15  = lane & 15;

  // median task: channel ci = t>>3 (0..31), pixel strip s = t&7 (8 px)
  const int ci  = t >> 3;
  const int s   = t & 7;
  const int px0 = s << 3;
  const int cw  = ci ^ ((s & 3) << 3);   // Bt bank-deconflict swizzle
  const bool rT = (r >= 1), rB = (r <= 62);
  const bool hasL = (s > 0), hasR = (s < 7);

  const float* xb = x + ((size_t)b << 20);   // b * 256*64*64

  // bias for this thread's 4 o-blocks (o = w*64 + n*16 + l15)
  float bn[4];
  #pragma unroll
  for (int n = 0; n < 4; ++n) bn[n] = bias[(w << 6) + (n << 4) + l15];

  // --- staging source byte-offsets (wave w stages rows w*24 .. w*24+23) ---
  unsigned soff[6];
  #pragma unroll
  for (int p = 0; p < 6; ++p) {
    int row = w * 24 + (p << 2) + (lane >> 4);
    int cip = (row * 171) >> 9;            // row / 3 (exact for row < 96)
    int drp = row - cip * 3;
    int gr  = r + drp - 1;
    gr = gr < 0 ? 0 : (gr > 63 ? 63 : gr); // clamp; zeroed in VALU at median time
    int bG  = (lane & 15) ^ (cip & 7);     // pre-swizzled global px-block
    soff[p] = ((unsigned)cip << 14) + ((unsigned)gr << 8) + ((unsigned)bG << 4);
  }

  // loop-invariant swizzled LDS read block indices
  const int ri0 = ci * 3;
  const int sig = ci & 7;
  const int bAi = ((s << 1)) ^ sig;
  const int bBi = ((s << 1) | 1) ^ sig;

  auto stage = [&](int step) {
    const unsigned kso = (unsigned)step << 19;   // step * 32ch * 4096px * 4B
    #pragma unroll
    for (int p = 0; p < 6; ++p)
      gload_lds16((const char*)xb + (soff[p] + kso), &Xs[w * 24 + (p << 2)][0]);
  };

  auto load_wf = [&](int step, bf16x8* wf) {
    #pragma unroll
    for (int n = 0; n < 4; ++n) {
      const int fidx = (((step << 4) + (w << 2) + n) << 6) + lane;
      wf[n] = __builtin_bit_cast(bf16x8, *(const u16x8*)(wbf + ((size_t)fidx << 3)));
    }
  };

  auto median_store = [&](int bufb) {
    f32x4 va[3], vb[3];
    #pragma unroll
    for (int dr = 0; dr < 3; ++dr) {
      const float* rp = &Xs[ri0 + dr][0];
      va[dr] = *(const f32x4*)(rp + (bAi << 2));
      vb[dr] = *(const f32x4*)(rp + (bBi << 2));
    }
    float R[3][10];
    #pragma unroll
    for (int dr = 0; dr < 3; ++dr) {
      float le = __shfl_up(vb[dr][3], 1);    // left halo from lane-1 (same wave)
      float re = __shfl_down(va[dr][0], 1);  // right halo from lane+1
      R[dr][0] = hasL ? le : 0.f;
      R[dr][9] = hasR ? re : 0.f;
      #pragma unroll
      for (int j = 0; j < 4; ++j) { R[dr][1 + j] = va[dr][j]; R[dr][5 + j] = vb[dr][j]; }
    }
    if (!rT) {                     // uniform per block (r==0 only)
      #pragma unroll
      for (int j = 0; j < 10; ++j) R[0][j] = 0.f;
    }
    if (!rB) {                     // uniform per block (r==63 only)
      #pragma unroll
      for (int j = 0; j < 10; ++j) R[2][j] = 0.f;
    }
    float mn[10], md[10], mx[10];
    #pragma unroll
    for (int j = 0; j < 10; ++j) {
      mn[j] = min3f(R[0][j], R[1][j], R[2][j]);
      md[j] = med3f(R[0][j], R[1][j], R[2][j]);
      mx[j] = max3f(R[0][j], R[1][j], R[2][j]);
    }
    #pragma unroll
    for (int i = 0; i < 8; ++i) {
      float t0 = max3f(mn[i], mn[i+1], mn[i+2]);
      float t1 = med3f(md[i], md[i+1], md[i+2]);
      float t2 = min3f(mx[i], mx[i+1], mx[i+2]);
      Bt[bufb][px0 + i][cw] = f2bf(med3f(t0, t1, t2));
    }
  };

  f32x4 acc[4][4];
  #pragma unroll
  for (int m = 0; m < 4; ++m)
    #pragma unroll
    for (int n = 0; n < 4; ++n)
      acc[m][n] = (f32x4){0.f, 0.f, 0.f, 0.f};

  bf16x8 wf[2][4];

  // --- prologue: stage(0) + wf(0) in flight ---
  stage(0);
  load_wf(0, wf[0]);

  #pragma unroll
  for (int ks = 0; ks < 8; ++ks) {
    // (a) per-wave drain: stage(ks) landed in this wave's Xs rows
    asm volatile("s_waitcnt vmcnt(0)" ::: "memory");
    __builtin_amdgcn_sched_barrier(0);

    // (b) median(ks): Xs -> Bt[ks&1]
    median_store(ks & 1);

    // (c,d) next step's stage + W fragments (stay in flight across barrier+MFMA)
    __builtin_amdgcn_sched_barrier(0);   // keep gload_lds below median's ds_reads
    if (ks < 7) {
      stage(ks + 1);
      load_wf(ks + 1, wf[(ks + 1) & 1]);
    }

    // (e) publish Bt: drain LDS ops only, raw barrier (NO vmcnt drain)
    asm volatile("s_waitcnt lgkmcnt(0)\n\ts_barrier" ::: "memory");
    __builtin_amdgcn_sched_barrier(0);

    // (f) P fragments (med tile, A-operand) from Bt[ks&1]
    bf16x8 pa[4];
    #pragma unroll
    for (int m = 0; m < 4; ++m) {
      const int px = (m << 4) + l15;
      const int gc = (g ^ ((px >> 3) & 3)) << 3;
      pa[m] = __builtin_bit_cast(bf16x8, *(const u16x8*)&Bt[ks & 1][px][gc]);
    }

    // (g) MFMA
    __builtin_amdgcn_s_setprio(1);
    #pragma unroll
    for (int m = 0; m < 4; ++m)
      #pragma unroll
      for (int n = 0; n < 4; ++n)
        acc[m][n] = __builtin_amdgcn_mfma_f32_16x16x32_bf16(pa[m], wf[ks & 1][n], acc[m][n], 0, 0, 0);
    __builtin_amdgcn_s_setprio(0);
  }

  // --- epilogue: out = x + acc + bias; q maps to px -> f32x4 I/O ---
  // C layout: row = g*4+q -> px = m*16+g*4+q ; col = l15 -> o = w*64+n*16+l15
  #pragma unroll
  for (int m = 0; m < 4; ++m) {
    #pragma unroll
    for (int n = 0; n < 4; ++n) {
      const int o = (w << 6) + (n << 4) + l15;
      const size_t idx = ((((size_t)b << 8) + (size_t)o) << 12) + ((size_t)r << 6)
                       + (size_t)((m << 4) + (g << 2));
      f32x4 xv = *(const f32x4*)(x + idx);
      f32x4 res;
      #pragma unroll
      for (int q = 0; q < 4; ++q) res[q] = xv[q] + acc[m][n][q] + bn[n];
      *(f32x4*)(out + idx) = res;
    }
  }
}

extern "C" void kernel_launch(void* const* d_in, const int* in_sizes, int n_in,
                              void* d_out, int out_size, void* d_ws, size_t ws_size,
                              hipStream_t stream) {
  const float* x  = (const float*)d_in[0];
  const float* cw = (const float*)d_in[1];
  const float* cb = (const float*)d_in[2];
  float* out = (float*)d_out;
  unsigned short* wbf = (unsigned short*)d_ws;   // 128 KB fragment-linear W

  hipLaunchKernelGGL(wconv_k, dim3(32), dim3(256), 0, stream, cw, wbf);
  hipLaunchKernelGGL(fused_k, dim3(2048), dim3(256), 0, stream, x, wbf, cb, out);
}